// Round 8
// baseline (3123.924 us; speedup 1.0000x reference)
//
#include <hip/hip_runtime.h>

// ObjectMsgEncoder on MI355X. f32 I/O, bf16 MFMA internally (f32 accumulate).
// R7 -> R8:
//  * k_mega: block = (scene, j-tile of 2): 56 pairs padded to 64 rows, Xb 64x264
//    (36KB LDS), 512 thr / 8 waves (wave = row-tile x col-half), Y[8], unroll-1.
//    All residency limits have margin -> 4 blocks/CU = 32 waves/CU (was 14).
//    R7 was latency-bound: MfmaUtil 4.6%, VALUBusy 14.9%, occupancy 42.7%.
//  * k_rec: 16 -> 32 blocks x 8 scenes (L2 BW scales with CUs engaged).
//  * 5 k_cvt launches merged into 1.
// ws: olf 11.0 + At 22.0 (zx aliases) + part 51.4 + wcv 1.7 = 86.1 MB.

typedef __attribute__((ext_vector_type(8))) short short8;
typedef __attribute__((ext_vector_type(4))) float f32x4;

__device__ __forceinline__ float b2f(unsigned short u){
  union { unsigned int i; float f; } v; v.i = ((unsigned int)u) << 16; return v.f;
}
__device__ __forceinline__ unsigned short f2b(float f){
  union { float f; unsigned int i; } v; v.f = f;
  unsigned int i = v.i;
  unsigned int r = (i + 0x7FFFu + ((i >> 16) & 1u)) >> 16;
  return (unsigned short)r;
}
__device__ __forceinline__ float sigm(float x){ return 1.f/(1.f+__expf(-x)); }
__device__ __forceinline__ float tanh_f(float x){ float e = __expf(2.f*x); return 1.f - 2.f/(e+1.f); }

#define MFMA16(a,b,c) __builtin_amdgcn_mfma_f32_16x16x32_bf16((a),(b),(c),0,0,0)

// ---------------- K0: f32 -> bf16 conversion of all 5 weight matrices ----------------
__global__ __launch_bounds__(256) void k_cvt5(const float* __restrict__ s0,
                                              const float* __restrict__ s1,
                                              const float* __restrict__ s2,
                                              const float* __restrict__ s3,
                                              const float* __restrict__ s4,
                                              unsigned short* __restrict__ dst){
  int i = blockIdx.x*256 + threadIdx.x;   // grid 3328*256 = 851,968 exactly
  const float* s; int off;
  if      (i < 262144){ s = s0; off = 0; }
  else if (i < 524288){ s = s1; off = 262144; }
  else if (i < 720896){ s = s2; off = 524288; }
  else if (i < 786432){ s = s3; off = 720896; }
  else                { s = s4; off = 786432; }
  dst[i] = f2b(s[i - off]);
}

// ---------------- K1: olf0 = emb * mask (f32 -> bf16) ----------------
__global__ __launch_bounds__(256) void k_prep(const float* __restrict__ emb,
                                              const int* __restrict__ counts,
                                              unsigned short* __restrict__ olf){
  int bs = blockIdx.x;            // b*28+s
  int b = bs / 28; int s = bs - b*28;
  int e = threadIdx.x;
  olf[(size_t)bs*256 + e] = (s < counts[b]) ? f2b(emb[(size_t)bs*256 + e]) : (unsigned short)0;
}

// ---------------- K2a: zx = olf_l @ Wih^T  [7168,256]@[256,1024] -> bf16 ----------------
__global__ __launch_bounds__(256) void k_xgemm(const unsigned short* __restrict__ olf,
                                               const unsigned short* __restrict__ Wih,
                                               unsigned short* __restrict__ zx){
  const int tid = threadIdx.x;
  const int wid = tid >> 6, lane = tid & 63, col = lane & 15, quad = lane >> 4;
  const int m0 = blockIdx.x*64 + wid*16;
  short8 af[8];
  #pragma unroll
  for (int kt=0; kt<8; ++kt)
    af[kt] = *(const short8*)&olf[(size_t)(m0 + col)*256 + kt*32 + quad*8];
  #pragma unroll 4
  for (int nt=0; nt<64; ++nt){
    int n = nt*16 + col;
    f32x4 acc = (f32x4){0.f,0.f,0.f,0.f};
    #pragma unroll
    for (int kt=0; kt<8; ++kt){
      short8 bf = *(const short8*)&Wih[(size_t)n*256 + kt*32 + quad*8];
      acc = MFMA16(af[kt], bf, acc);
    }
    #pragma unroll
    for (int r=0; r<4; ++r)
      zx[(size_t)(m0 + quad*4 + r)*1024 + n] = f2b(acc[r]);
  }
}

// ---------------- K2b: LSTM recurrence: 32 blocks x 8 scenes ----------------
__global__ __launch_bounds__(512) void k_rec(const unsigned short* __restrict__ zx,
                                             const unsigned short* __restrict__ Whh,
                                             const float* __restrict__ bih,
                                             const float* __restrict__ bhh,
                                             const int* __restrict__ counts,
                                             unsigned short* __restrict__ olf_out){
  __shared__ unsigned short Ab[16*264];   // rows 8..15 stay zero (MFMA padding)
  const int tid = threadIdx.x;
  const int wid = tid >> 6, lane = tid & 63, col = lane & 15, quad = lane >> 4;
  const int sc0 = blockIdx.x * 8;

  float bz[4][2];
  #pragma unroll
  for (int g=0; g<4; ++g){
    #pragma unroll
    for (int tt=0; tt<2; ++tt){
      int u = wid*32 + tt*16 + col;
      bz[g][tt] = bih[g*256+u] + bhh[g*256+u];
    }
  }
  int cnt4[4];
  #pragma unroll
  for (int r=0; r<4; ++r){
    int s = quad*4 + r;
    cnt4[r] = (s < 8) ? counts[sc0 + s] : 0;
  }

  float cst[2][4];
  #pragma unroll
  for (int tt=0; tt<2; ++tt){
    #pragma unroll
    for (int r=0; r<4; ++r) cst[tt][r] = 0.f;
  }
  for (int i=tid; i<16*264; i+=512) Ab[i] = 0;   // h0 = 0 (+ zero padding rows)
  __syncthreads();

  for (int t=0; t<28; ++t){
    float zxv[4][2][4];
    #pragma unroll
    for (int g=0; g<4; ++g){
      #pragma unroll
      for (int tt=0; tt<2; ++tt){
        #pragma unroll
        for (int r=0; r<4; ++r){
          int s = quad*4 + r;
          zxv[g][tt][r] = (s < 8)
            ? b2f(zx[((size_t)(sc0 + s)*28 + t)*1024 + g*256 + wid*32 + tt*16 + col])
            : 0.f;
        }
      }
    }
    f32x4 acc[4][2];
    #pragma unroll
    for (int g=0; g<4; ++g){
      #pragma unroll
      for (int tt=0; tt<2; ++tt) acc[g][tt] = (f32x4){0.f,0.f,0.f,0.f};
    }
    #pragma unroll
    for (int kt=0; kt<8; ++kt){
      short8 a = *(const short8*)&Ab[col*264 + kt*32 + quad*8];
      #pragma unroll
      for (int g=0; g<4; ++g){
        #pragma unroll
        for (int tt=0; tt<2; ++tt){
          int n = g*256 + wid*32 + tt*16 + col;
          short8 bf = *(const short8*)&Whh[(size_t)n*256 + kt*32 + quad*8];
          acc[g][tt] = MFMA16(a, bf, acc[g][tt]);
        }
      }
    }
    __syncthreads();   // all reads of Ab(t) done
    #pragma unroll
    for (int tt=0; tt<2; ++tt){
      #pragma unroll
      for (int r=0; r<4; ++r){
        int s = quad*4 + r;
        float zi = acc[0][tt][r] + zxv[0][tt][r] + bz[0][tt];
        float zf = acc[1][tt][r] + zxv[1][tt][r] + bz[1][tt];
        float zg = acc[2][tt][r] + zxv[2][tt][r] + bz[2][tt];
        float zo = acc[3][tt][r] + zxv[3][tt][r] + bz[3][tt];
        float cc = sigm(zf)*cst[tt][r] + sigm(zi)*tanh_f(zg);
        cst[tt][r] = cc;
        float hh = sigm(zo)*tanh_f(cc);
        if (s < 8){
          int u = wid*32 + tt*16 + col;
          unsigned short hb = f2b(hh);
          Ab[s*264 + u] = hb;                                 // raw h feeds recurrence
          olf_out[((size_t)(sc0+s)*28 + t)*256 + u] = (t < cnt4[r]) ? hb : (unsigned short)0;
        }
      }
    }
    __syncthreads();
  }
}

// ---------------- K3: A-terms, [21504,256]@[256,512] -> bf16 ----------------
__global__ __launch_bounds__(256) void k_aterm(const unsigned short* __restrict__ olf,
                                               const unsigned short* __restrict__ Wgr,
                                               unsigned short* __restrict__ Aout){
  const int tid = threadIdx.x;
  const int wid = tid >> 6, lane = tid & 63, col = lane & 15, quad = lane >> 4;
  const int m0 = blockIdx.x*64 + wid*16;
  short8 af[8];
  #pragma unroll
  for (int kt=0; kt<8; ++kt)
    af[kt] = *(const short8*)&olf[(size_t)(m0 + col)*256 + kt*32 + quad*8];
  #pragma unroll 4
  for (int nt=0; nt<32; ++nt){
    int n = nt*16 + col;   // n<256: A_i (Wgr cols 0..255); else A_j (cols 256..511)
    const unsigned short* wb = (nt < 16) ? (Wgr + n*768) : (Wgr + (n-256)*768 + 256);
    f32x4 acc = (f32x4){0.f,0.f,0.f,0.f};
    #pragma unroll
    for (int kt=0; kt<8; ++kt){
      short8 bf = *(const short8*)&wb[kt*32 + quad*8];
      acc = MFMA16(af[kt], bf, acc);
    }
    #pragma unroll
    for (int r=0; r<4; ++r)
      Aout[(size_t)(m0 + quad*4 + r)*512 + nt*16 + col] = f2b(acc[r]);
  }
}

// ---------------- K4: fused per-(scene, j-tile-of-2) pipeline ----------------
// 512 thr / 8 waves: wave = (row-tile rt = wv>>1 of 16 pairs, col-half ch = wv&1).
// 56 real pairs (p = i*2+jc) padded to 64 rows; padded rows finite, masked by pv.
// Static LDS: 64*264*2 + 64*4 + 512*4 + 2*4 = 36,104 B -> 4 blocks/CU.
__global__ __launch_bounds__(512) void k_mega(
    const float* __restrict__ centers, const int* __restrict__ counts,
    const float* __restrict__ Wr, const float* __restrict__ br,
    const unsigned short* __restrict__ Wgr, const float* __restrict__ bgr,
    const unsigned short* __restrict__ Wbc, const float* __restrict__ bbc,
    const float* __restrict__ alpha,
    const unsigned short* __restrict__ Wesa, const float* __restrict__ besa,
    const float* __restrict__ Wmu, const float* __restrict__ bmu,
    const unsigned short* __restrict__ Aterm, unsigned short* __restrict__ part){
  __shared__ unsigned short Xb[64*264];    // pair p = i*2+jc (i<28, jc<2), 256 cols
  __shared__ float gsb[64];
  __shared__ float lseB[512];              // [jc*256+o]: max + ln(sum exp) over i
  __shared__ float lseG[2];                // per jc
  const int tid = threadIdx.x;
  const int wv = tid >> 6;          // 0..7
  const int rt = wv >> 1;           // row-tile 0..3
  const int ch = wv & 1;            // column half 0/1
  const int lane = tid & 63, col = lane & 15, quad = lane >> 4;
  const int b = blockIdx.x / 14, jt = blockIdx.x - b*14;   // j = jt*2 + jc
  const int cb = counts[b];

  float av = alpha[0];
  float tv = sigm(av);
  float c1 = (1.f-tv)*(1.f-tv) + tv*tv;
  float c2 = 2.f*tv*(1.f-tv);

  int pis[4], pjs[4]; float pv[4];
  #pragma unroll
  for (int r=0; r<4; ++r){
    int p = rt*16 + quad*4 + r;         // local pair 0..63 (valid < 56)
    int i = p >> 1;
    pis[r] = (i < 27) ? i : 27;         // clamp padded rows into At bounds
    pjs[r] = jt*2 + (p & 1);
    pv[r] = (p < 56 && i < cb && pjs[r] < cb) ? 1.f : 0.f;
  }
  // S0: rlf0 = (mask_i*c_i - mask_j*c_j) @ Wr^T + br ; padded rows = 0
  {
    int m = tid >> 3, sub = tid & 7;    // m 0..63, 32 cols each
    int i = m >> 1, j = jt*2 + (m & 1);
    bool valid = (m < 56);
    float mi = (valid && i < cb) ? 1.f : 0.f;
    float mj = (valid && j < cb) ? 1.f : 0.f;
    const float* ci = centers + (b*28 + (valid ? i : 0))*3;
    const float* cj = centers + (b*28 + (valid ? j : 0))*3;
    float dx = mi*ci[0] - mj*cj[0];
    float dy = mi*ci[1] - mj*cj[1];
    float dz = mi*ci[2] - mj*cj[2];
    for (int e = sub*32; e < sub*32 + 32; ++e){
      float v = valid ? (dx*Wr[e*3] + dy*Wr[e*3+1] + dz*Wr[e*3+2] + br[e]) : 0.f;
      Xb[m*264 + e] = f2b(v);
    }
  }
  __syncthreads();

  const int arow = rt*16 + col;
  const int nbase = ch*128;
  f32x4 Y[8];
  #pragma unroll 1
  for (int l=0; l<3; ++l){
    // GEMM1: Y = rlf @ Wgr_r^T  (this wave's 16 rows x 128 cols)
    #pragma unroll
    for (int nt=0; nt<8; ++nt) Y[nt] = (f32x4){0.f,0.f,0.f,0.f};
    #pragma unroll 1
    for (int kt=0; kt<8; ++kt){
      short8 a = *(const short8*)&Xb[arow*264 + kt*32 + quad*8];
      #pragma unroll
      for (int nt=0; nt<8; ++nt){
        int n = nbase + nt*16 + col;
        short8 bf = *(const short8*)&Wgr[n*768 + 512 + kt*32 + quad*8];
        Y[nt] = MFMA16(a, bf, Y[nt]);
      }
    }
    __syncthreads();
    // S2: rlf_lin = Y + A_i + A_j + bgr -> Xb (bf16)
    int aib[4], ajb[4];
    #pragma unroll
    for (int r=0; r<4; ++r){
      aib[r] = (l*7168 + b*28 + pis[r])*512;
      ajb[r] = (l*7168 + b*28 + pjs[r])*512 + 256;
    }
    #pragma unroll
    for (int nt=0; nt<8; ++nt){
      int n = nbase + nt*16 + col;
      float bg = bgr[n];
      #pragma unroll
      for (int r=0; r<4; ++r){
        float v = Y[nt][r] + bg + b2f(Aterm[aib[r] + n]) + b2f(Aterm[ajb[r] + n]);
        Xb[(rt*16 + quad*4 + r)*264 + n] = f2b(v);
      }
    }
    __syncthreads();
    // GEMM2: Y = rlf_lin @ Wbc^T
    #pragma unroll
    for (int nt=0; nt<8; ++nt) Y[nt] = (f32x4){0.f,0.f,0.f,0.f};
    #pragma unroll 1
    for (int kt=0; kt<8; ++kt){
      short8 a = *(const short8*)&Xb[arow*264 + kt*32 + quad*8];
      #pragma unroll
      for (int nt=0; nt<8; ++nt){
        int n = nbase + nt*16 + col;
        short8 bf = *(const short8*)&Wbc[n*256 + kt*32 + quad*8];
        Y[nt] = MFMA16(a, bf, Y[nt]);
      }
    }
    __syncthreads();
    // S4: rlf = tanh(c1*rlf_lin + c2*(CP+bbc)) * pv ; padded rows -> 0
    #pragma unroll
    for (int nt=0; nt<8; ++nt){
      int n = nbase + nt*16 + col;
      float bb = bbc[n];
      #pragma unroll
      for (int r=0; r<4; ++r){
        int off = (rt*16 + quad*4 + r)*264 + n;
        float rl = b2f(Xb[off]);
        float bez = c1*rl + c2*(Y[nt][r] + bb);
        Xb[off] = f2b(tanh_f(bez) * pv[r]);
      }
    }
    __syncthreads();
  }
  // S5: resa = rlf @ Wesa^T + besa -> Xb (bf16)
  #pragma unroll
  for (int nt=0; nt<8; ++nt) Y[nt] = (f32x4){0.f,0.f,0.f,0.f};
  #pragma unroll 1
  for (int kt=0; kt<8; ++kt){
    short8 a = *(const short8*)&Xb[arow*264 + kt*32 + quad*8];
    #pragma unroll
    for (int nt=0; nt<8; ++nt){
      int n = nbase + nt*16 + col;
      short8 bf = *(const short8*)&Wesa[n*256 + kt*32 + quad*8];
      Y[nt] = MFMA16(a, bf, Y[nt]);
    }
  }
  __syncthreads();   // all reads of rlf done before overwrite with resa
  #pragma unroll
  for (int nt=0; nt<8; ++nt){
    int n = nbase + nt*16 + col;
    float be = besa[n];
    #pragma unroll
    for (int r=0; r<4; ++r)
      Xb[(rt*16 + quad*4 + r)*264 + n] = f2b(Y[nt][r] + be);
  }
  __syncthreads();
  // gscore from post-esa Xb: 8 threads per pair
  {
    int m = tid >> 3, sub = tid & 7;
    float s = 0.f;
    for (int e = sub*32; e < sub*32 + 32; ++e){
      float wm = Wmu[e] + Wmu[256+e] + Wmu[512+e];
      s += b2f(Xb[m*264 + e]) * wm;
    }
    s += __shfl_xor(s, 1, 64);
    s += __shfl_xor(s, 2, 64);
    s += __shfl_xor(s, 4, 64);
    if (sub == 0)
      gsb[m] = s*(1.f/3.f) + (bmu[0] + bmu[1] + bmu[2])*(1.f/3.f);
  }
  __syncthreads();
  // softmax stats over i (28 rows) per (jc,o) and per jc: lse = max + ln(sum exp)
  {
    int it = tid;
    if (it < 512){
      int jc = it >> 8, o = it & 255;
      float mx = -1e30f;
      for (int i=0;i<28;++i) mx = fmaxf(mx, b2f(Xb[(i*2+jc)*264 + o]));
      float se = 0.f;
      for (int i=0;i<28;++i) se += __expf(b2f(Xb[(i*2+jc)*264 + o]) - mx);
      lseB[it] = mx + __logf(se);
    }
  }
  if (tid < 2){
    int jc = tid;
    float mx = -1e30f;
    for (int i=0;i<28;++i) mx = fmaxf(mx, gsb[i*2+jc]);
    float se = 0.f;
    for (int i=0;i<28;++i) se += __expf(gsb[i*2+jc] - mx);
    lseG[jc] = mx + __logf(se);
  }
  __syncthreads();
  // partial output: sum over the block's 2 j's
  for (int it = tid; it < 7168; it += 512){
    int i = it >> 8, o = it & 255;
    float acc = 0.f;
    #pragma unroll
    for (int jc=0; jc<2; ++jc){
      int p = i*2 + jc;
      float v = b2f(Xb[p*264 + o]);
      float a = 0.5f*__expf(v - lseB[jc*256+o])
              + 0.5f*__expf(gsb[p] - lseG[jc]);
      acc += a * v;
    }
    part[((size_t)blockIdx.x*28 + i)*256 + o] = f2b(acc);
  }
}

// ---------------- K5: reduce 14 j-tiles, mask, write f32 ----------------
__global__ __launch_bounds__(256) void k_out(const unsigned short* __restrict__ part,
                                             const int* __restrict__ counts,
                                             float* __restrict__ out){
  int b = blockIdx.x / 28, i = blockIdx.x - b*28, o = threadIdx.x;
  float acc = 0.f;
  #pragma unroll
  for (int jt=0; jt<14; ++jt)
    acc += b2f(part[(((size_t)(b*14 + jt))*28 + i)*256 + o]);
  if (i >= counts[b]) acc = 0.f;
  out[(size_t)blockIdx.x*256 + o] = acc;
}

extern "C" void kernel_launch(void* const* d_in, const int* in_sizes, int n_in,
                              void* d_out, int out_size, void* d_ws, size_t ws_size,
                              hipStream_t stream){
  const float* centers = (const float*)d_in[0];
  const float* emb     = (const float*)d_in[1];
  const int*   counts  = (const int*)d_in[2];
  const float* Wr      = (const float*)d_in[3];
  const float* br      = (const float*)d_in[4];
  const float* Wih     = (const float*)d_in[5];
  const float* Whh     = (const float*)d_in[6];
  const float* bih     = (const float*)d_in[7];
  const float* bhh     = (const float*)d_in[8];
  const float* Wgr     = (const float*)d_in[9];
  const float* bgr     = (const float*)d_in[10];
  const float* Wbc     = (const float*)d_in[11];
  const float* bbc     = (const float*)d_in[12];
  const float* alpha   = (const float*)d_in[13];
  const float* Wesa    = (const float*)d_in[14];
  const float* besa    = (const float*)d_in[15];
  const float* Wmu     = (const float*)d_in[16];
  const float* bmu     = (const float*)d_in[17];
  // d_in[18], d_in[19] (Wlv, blv) are dead at eval time.

  // ws layout (86,114,304 bytes total):
  unsigned short* olf  = (unsigned short*)d_ws;                        // 3*7168*256 bf16 = 11,010,048 B
  unsigned short* At   = (unsigned short*)((char*)d_ws + 11010048);    // 3*7168*512 bf16 = 22,020,096 B
  unsigned short* zx   = At;                                           // 7168*1024 bf16 (aliases At; used before k_aterm)
  unsigned short* part = (unsigned short*)((char*)d_ws + 33030144);    // 3584*28*256 bf16 = 51,380,224 B
  unsigned short* wcv  = (unsigned short*)((char*)d_ws + 84410368);    // 851,968 bf16 = 1,703,936 B
  unsigned short* cWih  = wcv;            // 262144
  unsigned short* cWhh  = wcv + 262144;   // 262144
  unsigned short* cWgr  = wcv + 524288;   // 196608
  unsigned short* cWbc  = wcv + 720896;   // 65536
  unsigned short* cWesa = wcv + 786432;   // 65536
  float* outp = (float*)d_out;

  hipLaunchKernelGGL(k_cvt5, dim3(3328), dim3(256), 0, stream, Wih, Whh, Wgr, Wbc, Wesa, wcv);

  hipLaunchKernelGGL(k_prep, dim3(7168), dim3(256), 0, stream, emb, counts, olf);
  // LSTM pass 1: olf0 -> olf1
  hipLaunchKernelGGL(k_xgemm, dim3(112), dim3(256), 0, stream, olf, cWih, zx);
  hipLaunchKernelGGL(k_rec,   dim3(32),  dim3(512), 0, stream, zx, cWhh, bih, bhh, counts,
                     olf + (size_t)7168*256);
  // LSTM pass 2: olf1 -> olf2
  hipLaunchKernelGGL(k_xgemm, dim3(112), dim3(256), 0, stream, olf + (size_t)7168*256, cWih, zx);
  hipLaunchKernelGGL(k_rec,   dim3(32),  dim3(512), 0, stream, zx, cWhh, bih, bhh, counts,
                     olf + (size_t)2*7168*256);
  hipLaunchKernelGGL(k_aterm, dim3(336), dim3(256), 0, stream, olf, cWgr, At);
  hipLaunchKernelGGL(k_mega,  dim3(3584), dim3(512), 0, stream,
                     centers, counts, Wr, br, cWgr, bgr, cWbc, bbc, alpha,
                     cWesa, besa, Wmu, bmu, At, part);
  hipLaunchKernelGGL(k_out,   dim3(7168), dim3(256), 0, stream, part, counts, outp);
}

// Round 9
// 2548.163 us; speedup vs baseline: 1.2260x; 1.2260x over previous
//
#include <hip/hip_runtime.h>

// ObjectMsgEncoder on MI355X. f32 I/O, bf16 MFMA internally (f32 accumulate).
// R8 -> R9: measured rule: usable LDS for co-residency = 64 KB/CU (R7: 64KB->1blk
// 42.7% occ; R8: 36KB->1blk 24.5% occ). k_mega re-engineered for 4 blocks/CU:
//  * j-tile = 1: 28 pairs pad to 32 rows; Xb = 32x256 bf16 = 16,384 B exactly.
//  * XOR chunk swizzle (chunk ^ (row&7)) instead of +8 column pad (bank spread).
//  * softmax stats embedded in Xb's 4 padding rows (epilogue-only).
//  * no 'part' buffer: f32 atomicAdd into outacc (zeroed in k_prep). ws = 42 MB.
//  * k_rec reverted to 16 blocks x 16 scenes (R7 config; R8's 32x8 regressed).

typedef __attribute__((ext_vector_type(8))) short short8;
typedef __attribute__((ext_vector_type(4))) float f32x4;

__device__ __forceinline__ float b2f(unsigned short u){
  union { unsigned int i; float f; } v; v.i = ((unsigned int)u) << 16; return v.f;
}
__device__ __forceinline__ unsigned short f2b(float f){
  union { float f; unsigned int i; } v; v.f = f;
  unsigned int i = v.i;
  unsigned int r = (i + 0x7FFFu + ((i >> 16) & 1u)) >> 16;
  return (unsigned short)r;
}
__device__ __forceinline__ float sigm(float x){ return 1.f/(1.f+__expf(-x)); }
__device__ __forceinline__ float tanh_f(float x){ float e = __expf(2.f*x); return 1.f - 2.f/(e+1.f); }
// Xb swizzle: 8-element (16B) chunks, phys = chunk ^ (row&7) in low 3 bits.
__device__ __forceinline__ int xsw(int row, int n){
  int c = n >> 3;
  int pc = (c & 24) | ((c ^ row) & 7);
  return row*256 + pc*8 + (n & 7);
}

#define MFMA16(a,b,c) __builtin_amdgcn_mfma_f32_16x16x32_bf16((a),(b),(c),0,0,0)

// ---------------- K0: f32 -> bf16 conversion of all 5 weight matrices ----------------
__global__ __launch_bounds__(256) void k_cvt5(const float* __restrict__ s0,
                                              const float* __restrict__ s1,
                                              const float* __restrict__ s2,
                                              const float* __restrict__ s3,
                                              const float* __restrict__ s4,
                                              unsigned short* __restrict__ dst){
  int i = blockIdx.x*256 + threadIdx.x;   // grid 3328*256 = 851,968 exactly
  const float* s; int off;
  if      (i < 262144){ s = s0; off = 0; }
  else if (i < 524288){ s = s1; off = 262144; }
  else if (i < 720896){ s = s2; off = 524288; }
  else if (i < 786432){ s = s3; off = 720896; }
  else                { s = s4; off = 786432; }
  dst[i] = f2b(s[i - off]);
}

// ---------------- K1: olf0 = emb * mask (f32 -> bf16) + zero outacc ----------------
__global__ __launch_bounds__(256) void k_prep(const float* __restrict__ emb,
                                              const int* __restrict__ counts,
                                              unsigned short* __restrict__ olf,
                                              float* __restrict__ outacc){
  int bs = blockIdx.x;            // b*28+s
  int b = bs / 28; int s = bs - b*28;
  int e = threadIdx.x;
  olf[(size_t)bs*256 + e] = (s < counts[b]) ? f2b(emb[(size_t)bs*256 + e]) : (unsigned short)0;
  outacc[(size_t)bs*256 + e] = 0.f;
}

// ---------------- K2a: zx = olf_l @ Wih^T  [7168,256]@[256,1024] -> bf16 ----------------
__global__ __launch_bounds__(256) void k_xgemm(const unsigned short* __restrict__ olf,
                                               const unsigned short* __restrict__ Wih,
                                               unsigned short* __restrict__ zx){
  const int tid = threadIdx.x;
  const int wid = tid >> 6, lane = tid & 63, col = lane & 15, quad = lane >> 4;
  const int m0 = blockIdx.x*64 + wid*16;
  short8 af[8];
  #pragma unroll
  for (int kt=0; kt<8; ++kt)
    af[kt] = *(const short8*)&olf[(size_t)(m0 + col)*256 + kt*32 + quad*8];
  #pragma unroll 4
  for (int nt=0; nt<64; ++nt){
    int n = nt*16 + col;
    f32x4 acc = (f32x4){0.f,0.f,0.f,0.f};
    #pragma unroll
    for (int kt=0; kt<8; ++kt){
      short8 bf = *(const short8*)&Wih[(size_t)n*256 + kt*32 + quad*8];
      acc = MFMA16(af[kt], bf, acc);
    }
    #pragma unroll
    for (int r=0; r<4; ++r)
      zx[(size_t)(m0 + quad*4 + r)*1024 + n] = f2b(acc[r]);
  }
}

// ---------------- K2b: LSTM recurrence (R7 config: 16 blocks x 16 scenes) ----------------
__global__ __launch_bounds__(512) void k_rec(const unsigned short* __restrict__ zx,
                                             const unsigned short* __restrict__ Whh,
                                             const float* __restrict__ bih,
                                             const float* __restrict__ bhh,
                                             const int* __restrict__ counts,
                                             unsigned short* __restrict__ olf_out){
  __shared__ unsigned short Ab[16*264];   // [scene][unit 0..255], stride 264
  const int tid = threadIdx.x;
  const int wid = tid >> 6, lane = tid & 63, col = lane & 15, quad = lane >> 4;
  const int sc0 = blockIdx.x * 16;

  float bz[4][2];
  #pragma unroll
  for (int g=0; g<4; ++g){
    #pragma unroll
    for (int tt=0; tt<2; ++tt){
      int u = wid*32 + tt*16 + col;
      bz[g][tt] = bih[g*256+u] + bhh[g*256+u];
    }
  }
  int cnt4[4];
  #pragma unroll
  for (int r=0; r<4; ++r) cnt4[r] = counts[sc0 + quad*4 + r];

  float cst[2][4];
  #pragma unroll
  for (int tt=0; tt<2; ++tt){
    #pragma unroll
    for (int r=0; r<4; ++r) cst[tt][r] = 0.f;
  }
  for (int i=tid; i<16*264; i+=512) Ab[i] = 0;   // h0 = 0
  __syncthreads();

  for (int t=0; t<28; ++t){
    float zxv[4][2][4];
    #pragma unroll
    for (int g=0; g<4; ++g){
      #pragma unroll
      for (int tt=0; tt<2; ++tt){
        #pragma unroll
        for (int r=0; r<4; ++r)
          zxv[g][tt][r] = b2f(zx[((size_t)(sc0 + quad*4 + r)*28 + t)*1024
                                 + g*256 + wid*32 + tt*16 + col]);
      }
    }
    f32x4 acc[4][2];
    #pragma unroll
    for (int g=0; g<4; ++g){
      #pragma unroll
      for (int tt=0; tt<2; ++tt) acc[g][tt] = (f32x4){0.f,0.f,0.f,0.f};
    }
    #pragma unroll
    for (int kt=0; kt<8; ++kt){
      short8 a = *(const short8*)&Ab[col*264 + kt*32 + quad*8];
      #pragma unroll
      for (int g=0; g<4; ++g){
        #pragma unroll
        for (int tt=0; tt<2; ++tt){
          int n = g*256 + wid*32 + tt*16 + col;
          short8 bf = *(const short8*)&Whh[(size_t)n*256 + kt*32 + quad*8];
          acc[g][tt] = MFMA16(a, bf, acc[g][tt]);
        }
      }
    }
    __syncthreads();   // all reads of Ab(t) done
    #pragma unroll
    for (int tt=0; tt<2; ++tt){
      #pragma unroll
      for (int r=0; r<4; ++r){
        int s = quad*4 + r;
        int u = wid*32 + tt*16 + col;
        float zi = acc[0][tt][r] + zxv[0][tt][r] + bz[0][tt];
        float zf = acc[1][tt][r] + zxv[1][tt][r] + bz[1][tt];
        float zg = acc[2][tt][r] + zxv[2][tt][r] + bz[2][tt];
        float zo = acc[3][tt][r] + zxv[3][tt][r] + bz[3][tt];
        float cc = sigm(zf)*cst[tt][r] + sigm(zi)*tanh_f(zg);
        cst[tt][r] = cc;
        float hh = sigm(zo)*tanh_f(cc);
        unsigned short hb = f2b(hh);
        Ab[s*264 + u] = hb;                                   // raw h feeds recurrence
        olf_out[((size_t)(sc0+s)*28 + t)*256 + u] = (t < cnt4[r]) ? hb : (unsigned short)0;
      }
    }
    __syncthreads();
  }
}

// ---------------- K3: A-terms, [21504,256]@[256,512] -> bf16 ----------------
__global__ __launch_bounds__(256) void k_aterm(const unsigned short* __restrict__ olf,
                                               const unsigned short* __restrict__ Wgr,
                                               unsigned short* __restrict__ Aout){
  const int tid = threadIdx.x;
  const int wid = tid >> 6, lane = tid & 63, col = lane & 15, quad = lane >> 4;
  const int m0 = blockIdx.x*64 + wid*16;
  short8 af[8];
  #pragma unroll
  for (int kt=0; kt<8; ++kt)
    af[kt] = *(const short8*)&olf[(size_t)(m0 + col)*256 + kt*32 + quad*8];
  #pragma unroll 4
  for (int nt=0; nt<32; ++nt){
    int n = nt*16 + col;   // n<256: A_i (Wgr cols 0..255); else A_j (cols 256..511)
    const unsigned short* wb = (nt < 16) ? (Wgr + n*768) : (Wgr + (n-256)*768 + 256);
    f32x4 acc = (f32x4){0.f,0.f,0.f,0.f};
    #pragma unroll
    for (int kt=0; kt<8; ++kt){
      short8 bf = *(const short8*)&wb[kt*32 + quad*8];
      acc = MFMA16(af[kt], bf, acc);
    }
    #pragma unroll
    for (int r=0; r<4; ++r)
      Aout[(size_t)(m0 + quad*4 + r)*512 + nt*16 + col] = f2b(acc[r]);
  }
}

// ---------------- K4: fused per-(scene, single-j) pipeline ----------------
// 512 thr / 8 waves: wave = (row-group rg = wv>>2 of 16 rows, col-quarter cq = wv&3).
// 28 real pairs (p = i) padded to 32 rows. Xb = 32*256*2 = 16,384 B TOTAL LDS
// -> 4 blocks/CU under the measured 64 KB/CU co-residency limit.
// Stats (lseB[256], gsb[32], lseG) live in Xb's pad rows 28..31 (epilogue only).
__global__ __launch_bounds__(512) void k_mega(
    const float* __restrict__ centers, const int* __restrict__ counts,
    const float* __restrict__ Wr, const float* __restrict__ br,
    const unsigned short* __restrict__ Wgr, const float* __restrict__ bgr,
    const unsigned short* __restrict__ Wbc, const float* __restrict__ bbc,
    const float* __restrict__ alpha,
    const unsigned short* __restrict__ Wesa, const float* __restrict__ besa,
    const float* __restrict__ Wmu, const float* __restrict__ bmu,
    const unsigned short* __restrict__ Aterm, float* __restrict__ outacc){
  __shared__ unsigned short Xb[32*256];    // 16,384 B exactly; rows 28-31 = pad/stats
  float* lseBp = (float*)&Xb[28*256];      // 256 f32 (rows 28-29)
  float* gsbp  = (float*)&Xb[30*256];      // 32 f32
  float* lseGp = (float*)&Xb[30*256 + 64]; // 1 f32
  const int tid = threadIdx.x;
  const int wv = tid >> 6;          // 0..7
  const int rg = wv >> 2;           // row-group 0..1 (16 rows each)
  const int cq = wv & 3;            // col-quarter 0..3 (64 cols each)
  const int lane = tid & 63, col = lane & 15, quad = lane >> 4;
  const int b = blockIdx.x / 28, j = blockIdx.x - b*28;
  const int cb = counts[b];

  float av = alpha[0];
  float tv = sigm(av);
  float c1 = (1.f-tv)*(1.f-tv) + tv*tv;
  float c2 = 2.f*tv*(1.f-tv);

  int pis[4]; float pv[4];
  #pragma unroll
  for (int r=0; r<4; ++r){
    int i = rg*16 + quad*4 + r;        // local pair row = scene object i
    pis[r] = (i < 27) ? i : 27;        // clamp pad rows into At bounds
    pv[r] = (i < 28 && i < cb && j < cb) ? 1.f : 0.f;
  }
  // S0: rlf0[i] = (mask_i*c_i - mask_j*c_j) @ Wr^T + br ; pad rows = 0
  {
    int m = tid >> 4, sub = tid & 15;  // m 0..31, 16 cols each
    bool valid = (m < 28);
    float mi = (valid && m < cb) ? 1.f : 0.f;
    float mj = (valid && j < cb) ? 1.f : 0.f;
    const float* ci = centers + (b*28 + (valid ? m : 0))*3;
    const float* cj = centers + (b*28 + j)*3;
    float dx = mi*ci[0] - mj*cj[0];
    float dy = mi*ci[1] - mj*cj[1];
    float dz = mi*ci[2] - mj*cj[2];
    for (int e = sub*16; e < sub*16 + 16; ++e){
      float v = valid ? (dx*Wr[e*3] + dy*Wr[e*3+1] + dz*Wr[e*3+2] + br[e]) : 0.f;
      Xb[xsw(m, e)] = f2b(v);
    }
  }
  __syncthreads();

  const int arow = rg*16 + col;
  const int nbase = cq*64;
  f32x4 Y[4];
  #pragma unroll 1
  for (int l=0; l<3; ++l){
    // GEMM1: Y = rlf @ Wgr_r^T  (16 rows x 64 cols per wave)
    #pragma unroll
    for (int nt=0; nt<4; ++nt) Y[nt] = (f32x4){0.f,0.f,0.f,0.f};
    #pragma unroll 1
    for (int kt=0; kt<8; ++kt){
      int c = kt*4 + quad;
      short8 a = *(const short8*)&Xb[arow*256 + ((c & 24) | ((c ^ arow) & 7))*8];
      #pragma unroll
      for (int nt=0; nt<4; ++nt){
        int n = nbase + nt*16 + col;
        short8 bf = *(const short8*)&Wgr[n*768 + 512 + kt*32 + quad*8];
        Y[nt] = MFMA16(a, bf, Y[nt]);
      }
    }
    __syncthreads();
    // S2: rlf_lin = Y + A_i + A_j + bgr -> Xb (bf16)
    int aib[4];
    #pragma unroll
    for (int r=0; r<4; ++r) aib[r] = (l*7168 + b*28 + pis[r])*512;
    const int ajb = (l*7168 + b*28 + j)*512 + 256;
    #pragma unroll
    for (int nt=0; nt<4; ++nt){
      int n = nbase + nt*16 + col;
      float bg = bgr[n];
      float aj = b2f(Aterm[ajb + n]);
      #pragma unroll
      for (int r=0; r<4; ++r){
        float v = Y[nt][r] + bg + b2f(Aterm[aib[r] + n]) + aj;
        Xb[xsw(rg*16 + quad*4 + r, n)] = f2b(v);
      }
    }
    __syncthreads();
    // GEMM2: Y = rlf_lin @ Wbc^T
    #pragma unroll
    for (int nt=0; nt<4; ++nt) Y[nt] = (f32x4){0.f,0.f,0.f,0.f};
    #pragma unroll 1
    for (int kt=0; kt<8; ++kt){
      int c = kt*4 + quad;
      short8 a = *(const short8*)&Xb[arow*256 + ((c & 24) | ((c ^ arow) & 7))*8];
      #pragma unroll
      for (int nt=0; nt<4; ++nt){
        int n = nbase + nt*16 + col;
        short8 bf = *(const short8*)&Wbc[n*256 + kt*32 + quad*8];
        Y[nt] = MFMA16(a, bf, Y[nt]);
      }
    }
    __syncthreads();
    // S4: rlf = tanh(c1*rlf_lin + c2*(CP+bbc)) * pv
    #pragma unroll
    for (int nt=0; nt<4; ++nt){
      int n = nbase + nt*16 + col;
      float bb = bbc[n];
      #pragma unroll
      for (int r=0; r<4; ++r){
        int off = xsw(rg*16 + quad*4 + r, n);
        float rl = b2f(Xb[off]);
        float bez = c1*rl + c2*(Y[nt][r] + bb);
        Xb[off] = f2b(tanh_f(bez) * pv[r]);
      }
    }
    __syncthreads();
  }
  // S5: resa = rlf @ Wesa^T + besa -> Xb (bf16)
  #pragma unroll
  for (int nt=0; nt<4; ++nt) Y[nt] = (f32x4){0.f,0.f,0.f,0.f};
  #pragma unroll 1
  for (int kt=0; kt<8; ++kt){
    int c = kt*4 + quad;
    short8 a = *(const short8*)&Xb[arow*256 + ((c & 24) | ((c ^ arow) & 7))*8];
    #pragma unroll
    for (int nt=0; nt<4; ++nt){
      int n = nbase + nt*16 + col;
      short8 bf = *(const short8*)&Wesa[n*256 + kt*32 + quad*8];
      Y[nt] = MFMA16(a, bf, Y[nt]);
    }
  }
  __syncthreads();   // all reads of rlf done before overwrite with resa
  #pragma unroll
  for (int nt=0; nt<4; ++nt){
    int n = nbase + nt*16 + col;
    float be = besa[n];
    #pragma unroll
    for (int r=0; r<4; ++r)
      Xb[xsw(rg*16 + quad*4 + r, n)] = f2b(Y[nt][r] + be);
  }
  __syncthreads();
  // gscore (rows < 28 only; write into pad-row stats area) + lseB per o
  {
    int m = tid >> 4, sub = tid & 15;
    if (m < 28){
      float s = 0.f;
      for (int e = sub*16; e < sub*16 + 16; ++e){
        float wm = Wmu[e] + Wmu[256+e] + Wmu[512+e];
        s += b2f(Xb[xsw(m, e)]) * wm;
      }
      s += __shfl_xor(s, 1, 64);
      s += __shfl_xor(s, 2, 64);
      s += __shfl_xor(s, 4, 64);
      s += __shfl_xor(s, 8, 64);
      if (sub == 0)
        gsbp[m] = s*(1.f/3.f) + (bmu[0] + bmu[1] + bmu[2])*(1.f/3.f);
    }
  }
  if (tid < 256){
    int o = tid;
    float mx = -1e30f;
    for (int i=0;i<28;++i) mx = fmaxf(mx, b2f(Xb[xsw(i, o)]));
    float se = 0.f;
    for (int i=0;i<28;++i) se += __expf(b2f(Xb[xsw(i, o)]) - mx);
    lseBp[o] = mx + __logf(se);
  }
  __syncthreads();
  if (tid == 0){
    float mx = -1e30f;
    for (int i=0;i<28;++i) mx = fmaxf(mx, gsbp[i]);
    float se = 0.f;
    for (int i=0;i<28;++i) se += __expf(gsbp[i] - mx);
    lseGp[0] = mx + __logf(se);
  }
  __syncthreads();
  // output contribution of this j: atomicAdd a*v into outacc[b][i][o]
  const float lseG = lseGp[0];
  for (int it = tid; it < 7168; it += 512){
    int i = it >> 8, o = it & 255;
    float v = b2f(Xb[xsw(i, o)]);
    float a = 0.5f*__expf(v - lseBp[o]) + 0.5f*__expf(gsbp[i] - lseG);
    atomicAdd(&outacc[((size_t)b*28 + i)*256 + o], a * v);
  }
}

// ---------------- K5: mask + write f32 ----------------
__global__ __launch_bounds__(256) void k_out(const float* __restrict__ outacc,
                                             const int* __restrict__ counts,
                                             float* __restrict__ out){
  int b = blockIdx.x / 28, i = blockIdx.x - b*28, o = threadIdx.x;
  float acc = outacc[(size_t)blockIdx.x*256 + o];
  if (i >= counts[b]) acc = 0.f;
  out[(size_t)blockIdx.x*256 + o] = acc;
}

extern "C" void kernel_launch(void* const* d_in, const int* in_sizes, int n_in,
                              void* d_out, int out_size, void* d_ws, size_t ws_size,
                              hipStream_t stream){
  const float* centers = (const float*)d_in[0];
  const float* emb     = (const float*)d_in[1];
  const int*   counts  = (const int*)d_in[2];
  const float* Wr      = (const float*)d_in[3];
  const float* br      = (const float*)d_in[4];
  const float* Wih     = (const float*)d_in[5];
  const float* Whh     = (const float*)d_in[6];
  const float* bih     = (const float*)d_in[7];
  const float* bhh     = (const float*)d_in[8];
  const float* Wgr     = (const float*)d_in[9];
  const float* bgr     = (const float*)d_in[10];
  const float* Wbc     = (const float*)d_in[11];
  const float* bbc     = (const float*)d_in[12];
  const float* alpha   = (const float*)d_in[13];
  const float* Wesa    = (const float*)d_in[14];
  const float* besa    = (const float*)d_in[15];
  const float* Wmu     = (const float*)d_in[16];
  const float* bmu     = (const float*)d_in[17];
  // d_in[18], d_in[19] (Wlv, blv) are dead at eval time.

  // ws layout (42,074,112 bytes total):
  unsigned short* olf    = (unsigned short*)d_ws;                      // 3*7168*256 bf16 = 11,010,048 B
  unsigned short* At     = (unsigned short*)((char*)d_ws + 11010048);  // 3*7168*512 bf16 = 22,020,096 B
  unsigned short* zx     = At;                                         // 7168*1024 bf16 (aliases At)
  float*          outacc = (float*)((char*)d_ws + 33030144);           // 7168*256 f32 = 7,340,032 B
  unsigned short* wcv    = (unsigned short*)((char*)d_ws + 40370176);  // 851,968 bf16 = 1,703,936 B
  unsigned short* cWih  = wcv;            // 262144
  unsigned short* cWhh  = wcv + 262144;   // 262144
  unsigned short* cWgr  = wcv + 524288;   // 196608
  unsigned short* cWbc  = wcv + 720896;   // 65536
  unsigned short* cWesa = wcv + 786432;   // 65536
  float* outp = (float*)d_out;

  hipLaunchKernelGGL(k_cvt5, dim3(3328), dim3(256), 0, stream, Wih, Whh, Wgr, Wbc, Wesa, wcv);

  hipLaunchKernelGGL(k_prep, dim3(7168), dim3(256), 0, stream, emb, counts, olf, outacc);
  // LSTM pass 1: olf0 -> olf1
  hipLaunchKernelGGL(k_xgemm, dim3(112), dim3(256), 0, stream, olf, cWih, zx);
  hipLaunchKernelGGL(k_rec,   dim3(16),  dim3(512), 0, stream, zx, cWhh, bih, bhh, counts,
                     olf + (size_t)7168*256);
  // LSTM pass 2: olf1 -> olf2
  hipLaunchKernelGGL(k_xgemm, dim3(112), dim3(256), 0, stream, olf + (size_t)7168*256, cWih, zx);
  hipLaunchKernelGGL(k_rec,   dim3(16),  dim3(512), 0, stream, zx, cWhh, bih, bhh, counts,
                     olf + (size_t)2*7168*256);
  hipLaunchKernelGGL(k_aterm, dim3(336), dim3(256), 0, stream, olf, cWgr, At);
  hipLaunchKernelGGL(k_mega,  dim3(7168), dim3(512), 0, stream,
                     centers, counts, Wr, br, cWgr, bgr, cWbc, bbc, alpha,
                     cWesa, besa, Wmu, bmu, At, outacc);
  hipLaunchKernelGGL(k_out,   dim3(7168), dim3(256), 0, stream, outacc, counts, outp);
}

// Round 10
// 1880.441 us; speedup vs baseline: 1.6613x; 1.3551x over previous
//
#include <hip/hip_runtime.h>

// ObjectMsgEncoder on MI355X. f32 I/O, bf16 MFMA internally (f32 accumulate).
// R9 -> R10: k_mega was latency-bound (MfmaUtil 5%, ~500 cyc per unroll-1 kt iter;
// occupancy was NOT the constraint - R7 1blk/CU == R9 2blk/CU time). Changes:
//  * wave tile 16x64 -> 32x32: 2 MFMAs per B-load (was 1), zero B duplication.
//  * kt-loop in chunks of 4: 16 loads (8 A + 8 B frags) issued together -> ILP.
//  * __launch_bounds__(512,4): 128-VGPR cap matching the real 2-blocks/CU residency.
// Everything else (LSTM split, A-terms, atomic epilogue) unchanged from R9.

typedef __attribute__((ext_vector_type(8))) short short8;
typedef __attribute__((ext_vector_type(4))) float f32x4;

__device__ __forceinline__ float b2f(unsigned short u){
  union { unsigned int i; float f; } v; v.i = ((unsigned int)u) << 16; return v.f;
}
__device__ __forceinline__ unsigned short f2b(float f){
  union { float f; unsigned int i; } v; v.f = f;
  unsigned int i = v.i;
  unsigned int r = (i + 0x7FFFu + ((i >> 16) & 1u)) >> 16;
  return (unsigned short)r;
}
__device__ __forceinline__ float sigm(float x){ return 1.f/(1.f+__expf(-x)); }
__device__ __forceinline__ float tanh_f(float x){ float e = __expf(2.f*x); return 1.f - 2.f/(e+1.f); }
// Xb swizzle: 8-element (16B) chunks, phys chunk = (c&24) | ((c^row)&7).
__device__ __forceinline__ int xsw(int row, int n){
  int c = n >> 3;
  int pc = (c & 24) | ((c ^ row) & 7);
  return row*256 + pc*8 + (n & 7);
}
__device__ __forceinline__ int xchunk(int row, int c){
  return row*256 + ((c & 24) | ((c ^ row) & 7))*8;
}

#define MFMA16(a,b,c) __builtin_amdgcn_mfma_f32_16x16x32_bf16((a),(b),(c),0,0,0)

// ---------------- K0: f32 -> bf16 conversion of all 5 weight matrices ----------------
__global__ __launch_bounds__(256) void k_cvt5(const float* __restrict__ s0,
                                              const float* __restrict__ s1,
                                              const float* __restrict__ s2,
                                              const float* __restrict__ s3,
                                              const float* __restrict__ s4,
                                              unsigned short* __restrict__ dst){
  int i = blockIdx.x*256 + threadIdx.x;   // grid 3328*256 = 851,968 exactly
  const float* s; int off;
  if      (i < 262144){ s = s0; off = 0; }
  else if (i < 524288){ s = s1; off = 262144; }
  else if (i < 720896){ s = s2; off = 524288; }
  else if (i < 786432){ s = s3; off = 720896; }
  else                { s = s4; off = 786432; }
  dst[i] = f2b(s[i - off]);
}

// ---------------- K1: olf0 = emb * mask (f32 -> bf16) + zero outacc ----------------
__global__ __launch_bounds__(256) void k_prep(const float* __restrict__ emb,
                                              const int* __restrict__ counts,
                                              unsigned short* __restrict__ olf,
                                              float* __restrict__ outacc){
  int bs = blockIdx.x;            // b*28+s
  int b = bs / 28; int s = bs - b*28;
  int e = threadIdx.x;
  olf[(size_t)bs*256 + e] = (s < counts[b]) ? f2b(emb[(size_t)bs*256 + e]) : (unsigned short)0;
  outacc[(size_t)bs*256 + e] = 0.f;
}

// ---------------- K2a: zx = olf_l @ Wih^T  [7168,256]@[256,1024] -> bf16 ----------------
__global__ __launch_bounds__(256) void k_xgemm(const unsigned short* __restrict__ olf,
                                               const unsigned short* __restrict__ Wih,
                                               unsigned short* __restrict__ zx){
  const int tid = threadIdx.x;
  const int wid = tid >> 6, lane = tid & 63, col = lane & 15, quad = lane >> 4;
  const int m0 = blockIdx.x*64 + wid*16;
  short8 af[8];
  #pragma unroll
  for (int kt=0; kt<8; ++kt)
    af[kt] = *(const short8*)&olf[(size_t)(m0 + col)*256 + kt*32 + quad*8];
  #pragma unroll 4
  for (int nt=0; nt<64; ++nt){
    int n = nt*16 + col;
    f32x4 acc = (f32x4){0.f,0.f,0.f,0.f};
    #pragma unroll
    for (int kt=0; kt<8; ++kt){
      short8 bf = *(const short8*)&Wih[(size_t)n*256 + kt*32 + quad*8];
      acc = MFMA16(af[kt], bf, acc);
    }
    #pragma unroll
    for (int r=0; r<4; ++r)
      zx[(size_t)(m0 + quad*4 + r)*1024 + n] = f2b(acc[r]);
  }
}

// ---------------- K2b: LSTM recurrence (16 blocks x 16 scenes) ----------------
__global__ __launch_bounds__(512) void k_rec(const unsigned short* __restrict__ zx,
                                             const unsigned short* __restrict__ Whh,
                                             const float* __restrict__ bih,
                                             const float* __restrict__ bhh,
                                             const int* __restrict__ counts,
                                             unsigned short* __restrict__ olf_out){
  __shared__ unsigned short Ab[16*264];   // [scene][unit 0..255], stride 264
  const int tid = threadIdx.x;
  const int wid = tid >> 6, lane = tid & 63, col = lane & 15, quad = lane >> 4;
  const int sc0 = blockIdx.x * 16;

  float bz[4][2];
  #pragma unroll
  for (int g=0; g<4; ++g){
    #pragma unroll
    for (int tt=0; tt<2; ++tt){
      int u = wid*32 + tt*16 + col;
      bz[g][tt] = bih[g*256+u] + bhh[g*256+u];
    }
  }
  int cnt4[4];
  #pragma unroll
  for (int r=0; r<4; ++r) cnt4[r] = counts[sc0 + quad*4 + r];

  float cst[2][4];
  #pragma unroll
  for (int tt=0; tt<2; ++tt){
    #pragma unroll
    for (int r=0; r<4; ++r) cst[tt][r] = 0.f;
  }
  for (int i=tid; i<16*264; i+=512) Ab[i] = 0;   // h0 = 0
  __syncthreads();

  for (int t=0; t<28; ++t){
    float zxv[4][2][4];
    #pragma unroll
    for (int g=0; g<4; ++g){
      #pragma unroll
      for (int tt=0; tt<2; ++tt){
        #pragma unroll
        for (int r=0; r<4; ++r)
          zxv[g][tt][r] = b2f(zx[((size_t)(sc0 + quad*4 + r)*28 + t)*1024
                                 + g*256 + wid*32 + tt*16 + col]);
      }
    }
    f32x4 acc[4][2];
    #pragma unroll
    for (int g=0; g<4; ++g){
      #pragma unroll
      for (int tt=0; tt<2; ++tt) acc[g][tt] = (f32x4){0.f,0.f,0.f,0.f};
    }
    #pragma unroll
    for (int kt=0; kt<8; ++kt){
      short8 a = *(const short8*)&Ab[col*264 + kt*32 + quad*8];
      #pragma unroll
      for (int g=0; g<4; ++g){
        #pragma unroll
        for (int tt=0; tt<2; ++tt){
          int n = g*256 + wid*32 + tt*16 + col;
          short8 bf = *(const short8*)&Whh[(size_t)n*256 + kt*32 + quad*8];
          acc[g][tt] = MFMA16(a, bf, acc[g][tt]);
        }
      }
    }
    __syncthreads();   // all reads of Ab(t) done
    #pragma unroll
    for (int tt=0; tt<2; ++tt){
      #pragma unroll
      for (int r=0; r<4; ++r){
        int s = quad*4 + r;
        int u = wid*32 + tt*16 + col;
        float zi = acc[0][tt][r] + zxv[0][tt][r] + bz[0][tt];
        float zf = acc[1][tt][r] + zxv[1][tt][r] + bz[1][tt];
        float zg = acc[2][tt][r] + zxv[2][tt][r] + bz[2][tt];
        float zo = acc[3][tt][r] + zxv[3][tt][r] + bz[3][tt];
        float cc = sigm(zf)*cst[tt][r] + sigm(zi)*tanh_f(zg);
        cst[tt][r] = cc;
        float hh = sigm(zo)*tanh_f(cc);
        unsigned short hb = f2b(hh);
        Ab[s*264 + u] = hb;                                   // raw h feeds recurrence
        olf_out[((size_t)(sc0+s)*28 + t)*256 + u] = (t < cnt4[r]) ? hb : (unsigned short)0;
      }
    }
    __syncthreads();
  }
}

// ---------------- K3: A-terms, [21504,256]@[256,512] -> bf16 ----------------
__global__ __launch_bounds__(256) void k_aterm(const unsigned short* __restrict__ olf,
                                               const unsigned short* __restrict__ Wgr,
                                               unsigned short* __restrict__ Aout){
  const int tid = threadIdx.x;
  const int wid = tid >> 6, lane = tid & 63, col = lane & 15, quad = lane >> 4;
  const int m0 = blockIdx.x*64 + wid*16;
  short8 af[8];
  #pragma unroll
  for (int kt=0; kt<8; ++kt)
    af[kt] = *(const short8*)&olf[(size_t)(m0 + col)*256 + kt*32 + quad*8];
  #pragma unroll 4
  for (int nt=0; nt<32; ++nt){
    int n = nt*16 + col;   // n<256: A_i (Wgr cols 0..255); else A_j (cols 256..511)
    const unsigned short* wb = (nt < 16) ? (Wgr + n*768) : (Wgr + (n-256)*768 + 256);
    f32x4 acc = (f32x4){0.f,0.f,0.f,0.f};
    #pragma unroll
    for (int kt=0; kt<8; ++kt){
      short8 bf = *(const short8*)&wb[kt*32 + quad*8];
      acc = MFMA16(af[kt], bf, acc);
    }
    #pragma unroll
    for (int r=0; r<4; ++r)
      Aout[(size_t)(m0 + quad*4 + r)*512 + nt*16 + col] = f2b(acc[r]);
  }
}

// ---------------- K4: fused per-(scene, single-j) pipeline ----------------
// 512 thr / 8 waves; wave wv owns cols wv*32..wv*32+31 for ALL 32 rows.
// Per kt: 2 A-frags + 2 B-frags -> 4 MFMAs (2 MFMA/B-load). kt chunks of 4:
// 16 loads in flight. Xb = 32x256 bf16 = 16,384 B; stats in pad rows 28..31.
#define GEMM_TILE(WPTR, WSTRIDE, WOFF)                                              \
  {                                                                                 \
    Ya[0][0]=Ya[0][1]=Ya[1][0]=Ya[1][1]=(f32x4){0.f,0.f,0.f,0.f};                   \
    _Pragma("unroll 1")                                                             \
    for (int kc=0; kc<2; ++kc){                                                     \
      short8 av0[4], av1[4], bv0[4], bv1[4];                                        \
      _Pragma("unroll")                                                             \
      for (int u=0; u<4; ++u){                                                      \
        int kt = kc*4 + u; int c = kt*4 + quad;                                     \
        av0[u] = *(const short8*)&Xb[xchunk(col, c)];                               \
        av1[u] = *(const short8*)&Xb[xchunk(16+col, c)];                            \
        bv0[u] = *(const short8*)&(WPTR)[(nbase+col)*(WSTRIDE) + (WOFF) + kt*32 + quad*8];      \
        bv1[u] = *(const short8*)&(WPTR)[(nbase+16+col)*(WSTRIDE) + (WOFF) + kt*32 + quad*8];   \
      }                                                                             \
      _Pragma("unroll")                                                             \
      for (int u=0; u<4; ++u){                                                      \
        Ya[0][0] = MFMA16(av0[u], bv0[u], Ya[0][0]);                                \
        Ya[1][0] = MFMA16(av1[u], bv0[u], Ya[1][0]);                                \
        Ya[0][1] = MFMA16(av0[u], bv1[u], Ya[0][1]);                                \
        Ya[1][1] = MFMA16(av1[u], bv1[u], Ya[1][1]);                                \
      }                                                                             \
    }                                                                               \
  }

__global__ __launch_bounds__(512, 4) void k_mega(
    const float* __restrict__ centers, const int* __restrict__ counts,
    const float* __restrict__ Wr, const float* __restrict__ br,
    const unsigned short* __restrict__ Wgr, const float* __restrict__ bgr,
    const unsigned short* __restrict__ Wbc, const float* __restrict__ bbc,
    const float* __restrict__ alpha,
    const unsigned short* __restrict__ Wesa, const float* __restrict__ besa,
    const float* __restrict__ Wmu, const float* __restrict__ bmu,
    const unsigned short* __restrict__ Aterm, float* __restrict__ outacc){
  __shared__ unsigned short Xb[32*256];    // 16,384 B; rows 28-31 = pad/stats
  float* lseBp = (float*)&Xb[28*256];      // 256 f32 (rows 28-29)
  float* gsbp  = (float*)&Xb[30*256];      // 32 f32
  float* lseGp = (float*)&Xb[30*256 + 64]; // 1 f32
  const int tid = threadIdx.x;
  const int wv = tid >> 6;          // 0..7 -> col slice
  const int lane = tid & 63, col = lane & 15, quad = lane >> 4;
  const int b = blockIdx.x / 28, j = blockIdx.x - b*28;
  const int cb = counts[b];
  const int nbase = wv*32;

  float av = alpha[0];
  float tv = sigm(av);
  float c1 = (1.f-tv)*(1.f-tv) + tv*tv;
  float c2 = 2.f*tv*(1.f-tv);

  int pis[2][4]; float pv[2][4];
  #pragma unroll
  for (int rf=0; rf<2; ++rf){
    #pragma unroll
    for (int r=0; r<4; ++r){
      int i = rf*16 + quad*4 + r;
      pis[rf][r] = (i < 27) ? i : 27;
      pv[rf][r] = (i < 28 && i < cb && j < cb) ? 1.f : 0.f;
    }
  }
  // S0: rlf0[i] = (mask_i*c_i - mask_j*c_j) @ Wr^T + br ; pad rows = 0
  {
    int m = tid >> 4, sub = tid & 15;  // m 0..31, 16 cols each
    bool valid = (m < 28);
    float mi = (valid && m < cb) ? 1.f : 0.f;
    float mj = (valid && j < cb) ? 1.f : 0.f;
    const float* ci = centers + (b*28 + (valid ? m : 0))*3;
    const float* cj = centers + (b*28 + j)*3;
    float dx = mi*ci[0] - mj*cj[0];
    float dy = mi*ci[1] - mj*cj[1];
    float dz = mi*ci[2] - mj*cj[2];
    for (int e = sub*16; e < sub*16 + 16; ++e){
      float v = valid ? (dx*Wr[e*3] + dy*Wr[e*3+1] + dz*Wr[e*3+2] + br[e]) : 0.f;
      Xb[xsw(m, e)] = f2b(v);
    }
  }
  __syncthreads();

  f32x4 Ya[2][2];
  #pragma unroll 1
  for (int l=0; l<3; ++l){
    // GEMM1: rlf_lin(partial) = rlf @ Wgr_r^T
    GEMM_TILE(Wgr, 768, 512);
    __syncthreads();
    // S2: rlf_lin = Y + A_i + A_j + bgr -> Xb (bf16)
    int aib[2][4];
    #pragma unroll
    for (int rf=0; rf<2; ++rf)
      #pragma unroll
      for (int r=0; r<4; ++r) aib[rf][r] = (l*7168 + b*28 + pis[rf][r])*512;
    const int ajb = (l*7168 + b*28 + j)*512 + 256;
    #pragma unroll
    for (int nt=0; nt<2; ++nt){
      int n = nbase + nt*16 + col;
      float bg = bgr[n];
      float aj = b2f(Aterm[ajb + n]);
      #pragma unroll
      for (int rf=0; rf<2; ++rf){
        #pragma unroll
        for (int r=0; r<4; ++r){
          float v = Ya[rf][nt][r] + bg + b2f(Aterm[aib[rf][r] + n]) + aj;
          Xb[xsw(rf*16 + quad*4 + r, n)] = f2b(v);
        }
      }
    }
    __syncthreads();
    // GEMM2: CP = rlf_lin @ Wbc^T
    GEMM_TILE(Wbc, 256, 0);
    __syncthreads();
    // S4: rlf = tanh(c1*rlf_lin + c2*(CP+bbc)) * pv
    #pragma unroll
    for (int nt=0; nt<2; ++nt){
      int n = nbase + nt*16 + col;
      float bb = bbc[n];
      #pragma unroll
      for (int rf=0; rf<2; ++rf){
        #pragma unroll
        for (int r=0; r<4; ++r){
          int off = xsw(rf*16 + quad*4 + r, n);
          float rl = b2f(Xb[off]);
          float bez = c1*rl + c2*(Ya[rf][nt][r] + bb);
          Xb[off] = f2b(tanh_f(bez) * pv[rf][r]);
        }
      }
    }
    __syncthreads();
  }
  // S5: resa = rlf @ Wesa^T + besa -> Xb (bf16)
  GEMM_TILE(Wesa, 256, 0);
  __syncthreads();   // all reads of rlf done before overwrite with resa
  #pragma unroll
  for (int nt=0; nt<2; ++nt){
    int n = nbase + nt*16 + col;
    float be = besa[n];
    #pragma unroll
    for (int rf=0; rf<2; ++rf){
      #pragma unroll
      for (int r=0; r<4; ++r)
        Xb[xsw(rf*16 + quad*4 + r, n)] = f2b(Ya[rf][nt][r] + be);
    }
  }
  __syncthreads();
  // gscore (rows < 28; into pad-row stats) + lseB per o
  {
    int m = tid >> 4, sub = tid & 15;
    if (m < 28){
      float s = 0.f;
      for (int e = sub*16; e < sub*16 + 16; ++e){
        float wm = Wmu[e] + Wmu[256+e] + Wmu[512+e];
        s += b2f(Xb[xsw(m, e)]) * wm;
      }
      s += __shfl_xor(s, 1, 64);
      s += __shfl_xor(s, 2, 64);
      s += __shfl_xor(s, 4, 64);
      s += __shfl_xor(s, 8, 64);
      if (sub == 0)
        gsbp[m] = s*(1.f/3.f) + (bmu[0] + bmu[1] + bmu[2])*(1.f/3.f);
    }
  }
  if (tid < 256){
    int o = tid;
    float mx = -1e30f;
    for (int i=0;i<28;++i) mx = fmaxf(mx, b2f(Xb[xsw(i, o)]));
    float se = 0.f;
    for (int i=0;i<28;++i) se += __expf(b2f(Xb[xsw(i, o)]) - mx);
    lseBp[o] = mx + __logf(se);
  }
  __syncthreads();
  if (tid == 0){
    float mx = -1e30f;
    for (int i=0;i<28;++i) mx = fmaxf(mx, gsbp[i]);
    float se = 0.f;
    for (int i=0;i<28;++i) se += __expf(gsbp[i] - mx);
    lseGp[0] = mx + __logf(se);
  }
  __syncthreads();
  // output contribution of this j: atomicAdd a*v into outacc[b][i][o]
  const float lseG = lseGp[0];
  for (int it = tid; it < 7168; it += 512){
    int i = it >> 8, o = it & 255;
    float v = b2f(Xb[xsw(i, o)]);
    float a = 0.5f*__expf(v - lseBp[o]) + 0.5f*__expf(gsbp[i] - lseG);
    atomicAdd(&outacc[((size_t)b*28 + i)*256 + o], a * v);
  }
}

// ---------------- K5: mask + write f32 ----------------
__global__ __launch_bounds__(256) void k_out(const float* __restrict__ outacc,
                                             const int* __restrict__ counts,
                                             float* __restrict__ out){
  int b = blockIdx.x / 28, i = blockIdx.x - b*28, o = threadIdx.x;
  float acc = outacc[(size_t)blockIdx.x*256 + o];
  if (i >= counts[b]) acc = 0.f;
  out[(size_t)blockIdx.x*256 + o] = acc;
}

extern "C" void kernel_launch(void* const* d_in, const int* in_sizes, int n_in,
                              void* d_out, int out_size, void* d_ws, size_t ws_size,
                              hipStream_t stream){
  const float* centers = (const float*)d_in[0];
  const float* emb     = (const float*)d_in[1];
  const int*   counts  = (const int*)d_in[2];
  const float* Wr      = (const float*)d_in[3];
  const float* br      = (const float*)d_in[4];
  const float* Wih     = (const float*)d_in[5];
  const float* Whh     = (const float*)d_in[6];
  const float* bih     = (const float*)d_in[7];
  const float* bhh     = (const float*)d_in[8];
  const float* Wgr     = (const float*)d_in[9];
  const float* bgr     = (const float*)d_in[10];
  const float* Wbc     = (const float*)d_in[11];
  const float* bbc     = (const float*)d_in[12];
  const float* alpha   = (const float*)d_in[13];
  const float* Wesa    = (const float*)d_in[14];
  const float* besa    = (const float*)d_in[15];
  const float* Wmu     = (const float*)d_in[16];
  const float* bmu     = (const float*)d_in[17];
  // d_in[18], d_in[19] (Wlv, blv) are dead at eval time.

  // ws layout (42,074,112 bytes total):
  unsigned short* olf    = (unsigned short*)d_ws;                      // 3*7168*256 bf16 = 11,010,048 B
  unsigned short* At     = (unsigned short*)((char*)d_ws + 11010048);  // 3*7168*512 bf16 = 22,020,096 B
  unsigned short* zx     = At;                                         // 7168*1024 bf16 (aliases At)
  float*          outacc = (float*)((char*)d_ws + 33030144);           // 7168*256 f32 = 7,340,032 B
  unsigned short* wcv    = (unsigned short*)((char*)d_ws + 40370176);  // 851,968 bf16 = 1,703,936 B
  unsigned short* cWih  = wcv;            // 262144
  unsigned short* cWhh  = wcv + 262144;   // 262144
  unsigned short* cWgr  = wcv + 524288;   // 196608
  unsigned short* cWbc  = wcv + 720896;   // 65536
  unsigned short* cWesa = wcv + 786432;   // 65536
  float* outp = (float*)d_out;

  hipLaunchKernelGGL(k_cvt5, dim3(3328), dim3(256), 0, stream, Wih, Whh, Wgr, Wbc, Wesa, wcv);

  hipLaunchKernelGGL(k_prep, dim3(7168), dim3(256), 0, stream, emb, counts, olf, outacc);
  // LSTM pass 1: olf0 -> olf1
  hipLaunchKernelGGL(k_xgemm, dim3(112), dim3(256), 0, stream, olf, cWih, zx);
  hipLaunchKernelGGL(k_rec,   dim3(16),  dim3(512), 0, stream, zx, cWhh, bih, bhh, counts,
                     olf + (size_t)7168*256);
  // LSTM pass 2: olf1 -> olf2
  hipLaunchKernelGGL(k_xgemm, dim3(112), dim3(256), 0, stream, olf + (size_t)7168*256, cWih, zx);
  hipLaunchKernelGGL(k_rec,   dim3(16),  dim3(512), 0, stream, zx, cWhh, bih, bhh, counts,
                     olf + (size_t)2*7168*256);
  hipLaunchKernelGGL(k_aterm, dim3(336), dim3(256), 0, stream, olf, cWgr, At);
  hipLaunchKernelGGL(k_mega,  dim3(7168), dim3(512), 0, stream,
                     centers, counts, Wr, br, cWgr, bgr, cWbc, bbc, alpha,
                     cWesa, besa, Wmu, bmu, At, outacc);
  hipLaunchKernelGGL(k_out,   dim3(7168), dim3(256), 0, stream, outacc, counts, outp);
}